// Round 12
// baseline (251.900 us; speedup 1.0000x reference)
//
#include <hip/hip_runtime.h>
#include <hip/hip_bf16.h>

#define NN 100000
#define NE 1600000
#define NROWS 100096   // 782 * 128, padded row count for GEMM tiles
#define NBIN2 196      // ceil(NN/512) bins of 512 nodes (dst>>9)
#define NCHUNK 256     // edge chunks (= placement blocks)
#define EPB 6250       // edges per chunk (256*6250 = NE exactly)
#define CAPBIN 13312   // padded per-bin capacity (mean 8163 + pad <=3840 + slack)
#define SENT 0xFFFFFFFFu

typedef short bf16x8 __attribute__((ext_vector_type(8)));
typedef float f32x4 __attribute__((ext_vector_type(4)));

static __device__ __forceinline__ unsigned short f2bf(float f) {
    __hip_bfloat16 h = __float2bfloat16(f);
    return *reinterpret_cast<unsigned short*>(&h);
}
static __device__ __forceinline__ float bf2f(unsigned short u) {
    union { unsigned int i; float f; } v;
    v.i = ((unsigned int)u) << 16;
    return v.f;
}

#define GLOAD_LDS16(g, l) \
    __builtin_amdgcn_global_load_lds((const __attribute__((address_space(1))) void*)(g), \
                                     (__attribute__((address_space(3))) void*)(l), 16, 0, 0)

// ---------------- A1: per-chunk histogram over 196 bins ----------------
__global__ __launch_bounds__(256) void k_hist(const int* __restrict__ dst,
                                              int* __restrict__ hist) {
    __shared__ int lcnt[NBIN2];
    int k = blockIdx.x, t = threadIdx.x;
    if (t < NBIN2) lcnt[t] = 0;
    __syncthreads();
    int base = k * EPB;
    for (int i = t; i < EPB; i += 256) {
        int e = base + i;
        if (e < NE) atomicAdd(&lcnt[dst[e] >> 9], 1);
    }
    __syncthreads();
    if (t < NBIN2) hist[t * NCHUNK + k] = lcnt[t];   // [bin][chunk]
}

// ---------------- A2: per-bin scan over chunks (padded to 16) ----------------
__global__ __launch_bounds__(256) void k_scanA2a(const int* __restrict__ hist,
                                                 int* __restrict__ pbase,
                                                 int* __restrict__ ptot,
                                                 int* __restrict__ ttot) {
    __shared__ int shp[256];
    __shared__ int shv[256];
    int b = blockIdx.x, t = threadIdx.x;
    int v = hist[b * NCHUNK + t];
    int pv = (v + 15) & ~15;
    shp[t] = pv; shv[t] = v;
    __syncthreads();
    for (int d = 1; d < 256; d <<= 1) {
        int a1 = (t >= d) ? shp[t - d] : 0;
        int a2 = (t >= d) ? shv[t - d] : 0;
        __syncthreads();
        shp[t] += a1; shv[t] += a2;
        __syncthreads();
    }
    pbase[b * NCHUNK + t] = shp[t] - pv;   // exclusive padded base
    if (t == 255) { ptot[b] = shp[255]; ttot[b] = shv[255]; }
}

// ---------------- A3: deterministic placement (no global atomics) ----------------
__global__ __launch_bounds__(256) void k_placeA3(const int* __restrict__ src,
                                                 const int* __restrict__ dst,
                                                 const int* __restrict__ pbase,
                                                 unsigned int* __restrict__ pairs) {
    __shared__ int sbase[NBIN2];
    __shared__ int lcur[NBIN2];
    int k = blockIdx.x, t = threadIdx.x;
    if (t < NBIN2) { sbase[t] = pbase[t * NCHUNK + k]; lcur[t] = 0; }
    __syncthreads();
    int base = k * EPB;
    for (int i = t; i < EPB; i += 256) {
        int e = base + i;
        if (e < NE) {
            int s = src[e], d = dst[e];
            int b = d >> 9;
            int pos = atomicAdd(&lcur[b], 1);
            pairs[(long long)b * CAPBIN + sbase[b] + pos] =
                ((unsigned int)s << 9) | (unsigned int)(d & 511);
        }
    }
    __syncthreads();
    for (int b = t; b < NBIN2; b += 256) {
        int cnt = lcur[b];
        int end = sbase[b] + cnt;
        int pend = sbase[b] + ((cnt + 15) & ~15);
        for (int i = end; i < pend; ++i)
            pairs[(long long)b * CAPBIN + i] = SENT;
    }
}

// ---------------- B: per-bin (incl. inline 196-scan) -> off + ssrc ----------------
__global__ __launch_bounds__(512) void k_binPlace(const unsigned int* __restrict__ pairs,
                                                  const int* __restrict__ ptot,
                                                  const int* __restrict__ ttot,
                                                  int* __restrict__ off,
                                                  int* __restrict__ ssrc) {
    __shared__ int sbuf[9472];
    __shared__ int lcnt[512];
    __shared__ int sstart[512];
    __shared__ int lcur[512];
    __shared__ int sscan[512];
    __shared__ int stmp[512];
    __shared__ int sBB;
    int b = blockIdx.x, t = threadIdx.x;
    // inline exclusive-prefix over 196 true bin totals (replaces k_scanA2b)
    int tv = (t < NBIN2) ? ttot[t] : 0;
    stmp[t] = tv;
    lcnt[t] = 0; lcur[t] = 0;
    __syncthreads();
    for (int d = 1; d < 512; d <<= 1) {
        int add = (t >= d) ? stmp[t - d] : 0;
        __syncthreads();
        stmp[t] += add;
        __syncthreads();
    }
    if (t == 0) {
        sBB = (b == 0) ? 0 : stmp[b - 1];
        if (b == 0) off[NN] = NE;
    }
    __syncthreads();
    int bbase = sBB;
    int n = ptot[b];
    const unsigned int* pp = pairs + (long long)b * CAPBIN;
    for (int i = t; i < n; i += 512) {
        unsigned int p = pp[i];
        if (p != SENT) atomicAdd(&lcnt[p & 511], 1);
    }
    __syncthreads();
    int vv = lcnt[t];
    sscan[t] = vv;
    __syncthreads();
    for (int d = 1; d < 512; d <<= 1) {
        int add = (t >= d) ? sscan[t - d] : 0;
        __syncthreads();
        sscan[t] += add;
        __syncthreads();
    }
    sstart[t] = sscan[t] - vv;
    int node = b * 512 + t;
    if (node < NN) off[node] = bbase + sstart[t];
    __syncthreads();
    for (int i = t; i < n; i += 512) {
        unsigned int p = pp[i];
        if (p != SENT) {
            int dl = p & 511;
            int lp = atomicAdd(&lcur[dl], 1);
            sbuf[sstart[dl] + lp] = (int)(p >> 9);
        }
    }
    __syncthreads();
    int len = sscan[511];
    for (int i = t; i < len; i += 512)
        ssrc[bbase + i] = sbuf[i];
}

// ---------------- fused: convert x -> bf16 (blocks 0..12499) + weight prep (block 12500) ----------------
__global__ __launch_bounds__(256) void k_cvt_prep(const float* __restrict__ x,
                                                  unsigned short* __restrict__ Axcat,
                                                  const float* __restrict__ W1l,
                                                  const float* __restrict__ W1r,
                                                  const float* __restrict__ W2l,
                                                  const float* __restrict__ W2r,
                                                  unsigned short* __restrict__ Wcat1t,
                                                  unsigned short* __restrict__ Wcat2t) {
    if (blockIdx.x == 12500) {
        for (int i = threadIdx.x; i < 128 * 128; i += 256) {
            int n = i >> 7, k = i & 127;
            float v1 = (k < 64) ? W1l[k * 128 + n] : W1r[(k - 64) * 128 + n];
            Wcat1t[i] = f2bf(v1);
            float v2 = (n < 64) ? W2l[k * 64 + n] : W2r[k * 64 + (n - 64)];
            Wcat2t[i] = f2bf(v2);
        }
        return;
    }
    int idx = blockIdx.x * blockDim.x + threadIdx.x;  // node*32 + f2
    if (idx >= NN * 32) return;
    int node = idx >> 5, f2 = idx & 31;
    float2 v = *(const float2*)(x + (long long)node * 64 + 2 * f2);
    unsigned int p = (unsigned int)f2bf(v.x) | ((unsigned int)f2bf(v.y) << 16);
    *(unsigned int*)(Axcat + (long long)node * 128 + 64 + 2 * f2) = p;
}

// ---------------- gather-mean of x-half (dual-edge 8B loads, 16 edges in flight) ----------------
// 32 lanes per node; sub=lane>>4 picks edge of a pair; fl=lane&15 covers feats 4fl..4fl+3.
__global__ __launch_bounds__(256) void k_gather_x(const int* __restrict__ ssrc,
                                                  const int* __restrict__ off,
                                                  unsigned short* __restrict__ Axcat) {
    int wv = (blockIdx.x * blockDim.x + threadIdx.x) >> 6;
    int half = (threadIdx.x >> 5) & 1;
    int lane = threadIdx.x & 31;
    int node = wv * 2 + half;
    if (node >= NN) return;
    int sub = lane >> 4, fl = lane & 15;
    int o0 = off[node], o1 = off[node + 1];
    float a0 = 0.f, a1 = 0.f, a2 = 0.f, a3 = 0.f;
    for (int base = o0; base < o1; base += 32) {
        int nk = min(32, o1 - base);
        int sidx = (base + lane < o1) ? ssrc[base + lane] : 0;
        int k = 0;
        for (; k + 15 < nk; k += 16) {
            uint2 v[8];
            #pragma unroll
            for (int q = 0; q < 8; ++q) {
                int s = __shfl(sidx, k + 2 * q + sub, 32);
                v[q] = *(const uint2*)(Axcat + (long long)s * 128 + 64 + 4 * fl);
            }
            #pragma unroll
            for (int q = 0; q < 8; ++q) {
                a0 += bf2f((unsigned short)v[q].x); a1 += bf2f((unsigned short)(v[q].x >> 16));
                a2 += bf2f((unsigned short)v[q].y); a3 += bf2f((unsigned short)(v[q].y >> 16));
            }
        }
        for (; k < nk; k += 2) {
            float msk = (k + sub < nk) ? 1.f : 0.f;
            int s = __shfl(sidx, min(k + sub, nk - 1), 32);
            uint2 vv = *(const uint2*)(Axcat + (long long)s * 128 + 64 + 4 * fl);
            a0 += msk * bf2f((unsigned short)vv.x); a1 += msk * bf2f((unsigned short)(vv.x >> 16));
            a2 += msk * bf2f((unsigned short)vv.y); a3 += msk * bf2f((unsigned short)(vv.y >> 16));
        }
    }
    a0 += __shfl_xor(a0, 16, 32); a1 += __shfl_xor(a1, 16, 32);
    a2 += __shfl_xor(a2, 16, 32); a3 += __shfl_xor(a3, 16, 32);
    if (sub == 0) {
        int deg = o1 - o0;
        float inv = (deg > 0) ? 1.f / (float)deg : 0.f;
        uint2 p;
        p.x = (unsigned int)f2bf(a0 * inv) | ((unsigned int)f2bf(a1 * inv) << 16);
        p.y = (unsigned int)f2bf(a2 * inv) | ((unsigned int)f2bf(a3 * inv) << 16);
        *(uint2*)(Axcat + (long long)node * 128 + 4 * fl) = p;
    }
}

// ---------------- gather-mean of y1 + z + relu -> out (dual-edge 8B loads) ----------------
__global__ __launch_bounds__(256) void k_gather_out(const int* __restrict__ ssrc,
                                                    const int* __restrict__ off,
                                                    const unsigned short* __restrict__ y1b,
                                                    const unsigned short* __restrict__ zb,
                                                    float* __restrict__ out) {
    int wv = (blockIdx.x * blockDim.x + threadIdx.x) >> 6;
    int half = (threadIdx.x >> 5) & 1;
    int lane = threadIdx.x & 31;
    int node = wv * 2 + half;
    if (node >= NN) return;
    int sub = lane >> 4, fl = lane & 15;
    int o0 = off[node], o1 = off[node + 1];
    float a0 = 0.f, a1 = 0.f, a2 = 0.f, a3 = 0.f;
    for (int base = o0; base < o1; base += 32) {
        int nk = min(32, o1 - base);
        int sidx = (base + lane < o1) ? ssrc[base + lane] : 0;
        int k = 0;
        for (; k + 15 < nk; k += 16) {
            uint2 v[8];
            #pragma unroll
            for (int q = 0; q < 8; ++q) {
                int s = __shfl(sidx, k + 2 * q + sub, 32);
                v[q] = *(const uint2*)(y1b + (long long)s * 64 + 4 * fl);
            }
            #pragma unroll
            for (int q = 0; q < 8; ++q) {
                a0 += bf2f((unsigned short)v[q].x); a1 += bf2f((unsigned short)(v[q].x >> 16));
                a2 += bf2f((unsigned short)v[q].y); a3 += bf2f((unsigned short)(v[q].y >> 16));
            }
        }
        for (; k < nk; k += 2) {
            float msk = (k + sub < nk) ? 1.f : 0.f;
            int s = __shfl(sidx, min(k + sub, nk - 1), 32);
            uint2 vv = *(const uint2*)(y1b + (long long)s * 64 + 4 * fl);
            a0 += msk * bf2f((unsigned short)vv.x); a1 += msk * bf2f((unsigned short)(vv.x >> 16));
            a2 += msk * bf2f((unsigned short)vv.y); a3 += msk * bf2f((unsigned short)(vv.y >> 16));
        }
    }
    a0 += __shfl_xor(a0, 16, 32); a1 += __shfl_xor(a1, 16, 32);
    a2 += __shfl_xor(a2, 16, 32); a3 += __shfl_xor(a3, 16, 32);
    if (sub == 0) {
        int deg = o1 - o0;
        float inv = (deg > 0) ? 1.f / (float)deg : 0.f;
        uint2 zz = *(const uint2*)(zb + (long long)node * 64 + 4 * fl);
        float4 o;
        o.x = fmaxf(a0 * inv + bf2f((unsigned short)zz.x), 0.f);
        o.y = fmaxf(a1 * inv + bf2f((unsigned short)(zz.x >> 16)), 0.f);
        o.z = fmaxf(a2 * inv + bf2f((unsigned short)zz.y), 0.f);
        o.w = fmaxf(a3 * inv + bf2f((unsigned short)(zz.y >> 16)), 0.f);
        *(float4*)(out + (long long)node * 64 + 4 * fl) = o;
    }
}

// ---------------- fused MFMA GEMM: h1 = relu(A@Wc1+b1) in-LDS, then y1|z = h1@Wc2 ----------------
__global__ __launch_bounds__(256) void k_gemm_fused(
    const unsigned short* __restrict__ A,
    const unsigned short* __restrict__ Bt1,
    const unsigned short* __restrict__ Bt2,
    const float* __restrict__ b1,
    const float* __restrict__ b2,
    unsigned short* __restrict__ y1b,
    unsigned short* __restrict__ zb) {
    __shared__ unsigned short lds[3 * 128 * 128];  // [0,32K) A then h1; [32K,64K) Wc1; [64K,96K) Wc2
    __shared__ float sB1[128];
    __shared__ float sB2[128];
    const int tid = threadIdx.x;
    const int wid = tid >> 6;
    const int lane = tid & 63;

    if (tid < 128) {
        sB1[tid] = b1[tid];
        sB2[tid] = (tid >= 64) ? b2[tid - 64] : 0.f;  // pass-2 cols 64..127 carry b2
    }

    const char* Ag  = (const char*)(A + (long long)blockIdx.x * 128 * 128);
    const char* B1g = (const char*)Bt1;
    const char* B2g = (const char*)Bt2;
    char* ldsc = (char*)lds;
    #pragma unroll
    for (int j = 0; j < 8; ++j) {
        int g = wid * 512 + j * 64 + lane;        // granule (16B) index in [0,2048)
        int gs = g ^ ((g >> 4) & 7);              // pre-swizzled source granule
        GLOAD_LDS16(Ag  + (long long)gs * 16, ldsc + (wid * 8192 + j * 1024));
        GLOAD_LDS16(B1g + (long long)gs * 16, ldsc + 32768 + (wid * 8192 + j * 1024));
        GLOAD_LDS16(B2g + (long long)gs * 16, ldsc + 65536 + (wid * 8192 + j * 1024));
    }
    __syncthreads();

    const int rA = lane & 15;
    const int kq = lane >> 4;                     // 0..3
    f32x4 acc[2][8] = {};

    // ---- pass 1: h1 = A @ Wc1 ----
    #pragma unroll
    for (int ks = 0; ks < 4; ++ks) {
        const int kbyte = ks * 64 + kq * 16;
        bf16x8 a[2], b[8];
        #pragma unroll
        for (int m = 0; m < 2; ++m) {
            int row = wid * 32 + m * 16 + rA;
            a[m] = *(const bf16x8*)(ldsc + row * 256 + (kbyte ^ ((row & 7) << 4)));
        }
        #pragma unroll
        for (int n = 0; n < 8; ++n) {
            int row = n * 16 + rA;
            b[n] = *(const bf16x8*)(ldsc + 32768 + row * 256 + (kbyte ^ ((row & 7) << 4)));
        }
        #pragma unroll
        for (int m = 0; m < 2; ++m)
            #pragma unroll
            for (int n = 0; n < 8; ++n)
                acc[m][n] = __builtin_amdgcn_mfma_f32_16x16x32_bf16(a[m], b[n], acc[m][n], 0, 0, 0);
    }
    __syncthreads();   // all pass-1 A reads done before overwriting region 0 with h1

    // ---- write h1 = relu(acc + b1) into region 0, same swizzle as A reads ----
    #pragma unroll
    for (int m = 0; m < 2; ++m) {
        #pragma unroll
        for (int n = 0; n < 8; ++n) {
            int col = n * 16 + rA;
            int row0 = wid * 32 + m * 16 + kq * 4;
            #pragma unroll
            for (int r = 0; r < 4; ++r) {
                int row = row0 + r;
                float v = fmaxf(acc[m][n][r] + sB1[col], 0.f);
                *(unsigned short*)(ldsc + row * 256 + ((2 * col) ^ ((row & 7) << 4))) = f2bf(v);
            }
            acc[m][n] = f32x4{0.f, 0.f, 0.f, 0.f};   // reset for pass 2
        }
    }
    __syncthreads();

    // ---- pass 2: [y1|z] = h1 @ Wc2 ----
    #pragma unroll
    for (int ks = 0; ks < 4; ++ks) {
        const int kbyte = ks * 64 + kq * 16;
        bf16x8 a[2], b[8];
        #pragma unroll
        for (int m = 0; m < 2; ++m) {
            int row = wid * 32 + m * 16 + rA;
            a[m] = *(const bf16x8*)(ldsc + row * 256 + (kbyte ^ ((row & 7) << 4)));
        }
        #pragma unroll
        for (int n = 0; n < 8; ++n) {
            int row = n * 16 + rA;
            b[n] = *(const bf16x8*)(ldsc + 65536 + row * 256 + (kbyte ^ ((row & 7) << 4)));
        }
        #pragma unroll
        for (int m = 0; m < 2; ++m)
            #pragma unroll
            for (int n = 0; n < 8; ++n)
                acc[m][n] = __builtin_amdgcn_mfma_f32_16x16x32_bf16(a[m], b[n], acc[m][n], 0, 0, 0);
    }

    #pragma unroll
    for (int m = 0; m < 2; ++m) {
        #pragma unroll
        for (int n = 0; n < 8; ++n) {
            int col = n * 16 + rA;
            long long row0 = (long long)blockIdx.x * 128 + wid * 32 + m * 16 + kq * 4;
            #pragma unroll
            for (int r = 0; r < 4; ++r) {
                long long row = row0 + r;
                if (row < NN) {
                    float v = acc[m][n][r];
                    if (col < 64) y1b[row * 64 + col] = f2bf(v);
                    else          zb[row * 64 + (col - 64)] = f2bf(v + sB2[col]);
                }
            }
        }
    }
}

extern "C" void kernel_launch(void* const* d_in, const int* in_sizes, int n_in,
                              void* d_out, int out_size, void* d_ws, size_t ws_size,
                              hipStream_t stream) {
    const float* x   = (const float*)d_in[0];
    const int*   ei  = (const int*)d_in[1];
    const int*   src = ei;
    const int*   dst = ei + NE;
    const float* W1l = (const float*)d_in[2];
    const float* b1  = (const float*)d_in[3];
    const float* W1r = (const float*)d_in[4];
    const float* W2l = (const float*)d_in[5];
    const float* b2  = (const float*)d_in[6];
    const float* W2r = (const float*)d_in[7];
    float* out = (float*)d_out;

    // workspace layout (bytes), all buffers fully written before read (no memset):
    //   [0,        400640)    off    int[NN+1]
    //   [400640,   6800640)   ssrc   int[NE]
    //   [6800640,  7001344)   hist   int[NBIN2*NCHUNK]
    //   [7001344,  7202048)   pbase  int[NBIN2*NCHUNK]
    //   [7202048,  7203072)   ptot   int[256]
    //   [7203072,  7204096)   ttot   int[256]
    //   [7204096,  17640704)  pairs  uint[NBIN2*CAPBIN]
    //   [17640704, 43265280)  Axcat  bf16[NROWS][128]
    //   [43265280, 56065280)  y1b    bf16[NN][64]
    //   [56065280, 68865280)  zb     bf16[NN][64]
    //   [68865280, 68898048)  Wc1    bf16[128][128]
    //   [68898048, 68930816)  Wc2    bf16[128][128]
    char* ws = (char*)d_ws;
    int*   off   = (int*)ws;
    int*   ssrc  = (int*)(ws + 400640);
    int*   hist  = (int*)(ws + 6800640);
    int*   pbase = (int*)(ws + 7001344);
    int*   ptot  = (int*)(ws + 7202048);
    int*   ttot  = (int*)(ws + 7203072);
    unsigned int* pairs = (unsigned int*)(ws + 7204096);
    unsigned short* Axcat = (unsigned short*)(ws + 17640704);
    unsigned short* y1b   = (unsigned short*)(ws + 43265280);
    unsigned short* zb    = (unsigned short*)(ws + 56065280);
    unsigned short* Wc1   = (unsigned short*)(ws + 68865280);
    unsigned short* Wc2   = (unsigned short*)(ws + 68898048);

    k_hist<<<NCHUNK, 256, 0, stream>>>(dst, hist);
    k_scanA2a<<<NBIN2, 256, 0, stream>>>(hist, pbase, ptot, ttot);
    k_placeA3<<<NCHUNK, 256, 0, stream>>>(src, dst, pbase, pairs);
    k_binPlace<<<NBIN2, 512, 0, stream>>>(pairs, ptot, ttot, off, ssrc);
    k_cvt_prep<<<12501, 256, 0, stream>>>(x, Axcat, W1l, W1r, W2l, W2r, Wc1, Wc2);
    k_gather_x<<<(NN / 2 * 64 + 255) / 256, 256, 0, stream>>>(ssrc, off, Axcat);
    k_gemm_fused<<<NROWS / 128, 256, 0, stream>>>(Axcat, Wc1, Wc2, b1, b2, y1b, zb);
    k_gather_out<<<(NN / 2 * 64 + 255) / 256, 256, 0, stream>>>(ssrc, off, y1b, zb, out);
}

// Round 13
// 243.912 us; speedup vs baseline: 1.0328x; 1.0328x over previous
//
#include <hip/hip_runtime.h>
#include <hip/hip_bf16.h>

#define NN 100000
#define NE 1600000
#define NROWS 100096   // 782 * 128, padded row count for GEMM tiles
#define NBIN2 196      // ceil(NN/512) bins of 512 nodes (dst>>9)
#define NCHUNK 256     // edge chunks (= placement blocks)
#define EPB 6250       // edges per chunk (256*6250 = NE exactly)
#define CAPBIN 13312   // padded per-bin capacity (mean 8163 + pad <=3840 + slack)
#define SENT 0xFFFFFFFFu

typedef short bf16x8 __attribute__((ext_vector_type(8)));
typedef float f32x4 __attribute__((ext_vector_type(4)));

static __device__ __forceinline__ unsigned short f2bf(float f) {
    __hip_bfloat16 h = __float2bfloat16(f);
    return *reinterpret_cast<unsigned short*>(&h);
}
static __device__ __forceinline__ float bf2f(unsigned short u) {
    union { unsigned int i; float f; } v;
    v.i = ((unsigned int)u) << 16;
    return v.f;
}

#define GLOAD_LDS16(g, l) \
    __builtin_amdgcn_global_load_lds((const __attribute__((address_space(1))) void*)(g), \
                                     (__attribute__((address_space(3))) void*)(l), 16, 0, 0)

// ---------------- A1: per-chunk histogram over 196 bins ----------------
__global__ __launch_bounds__(256) void k_hist(const int* __restrict__ dst,
                                              int* __restrict__ hist) {
    __shared__ int lcnt[NBIN2];
    int k = blockIdx.x, t = threadIdx.x;
    if (t < NBIN2) lcnt[t] = 0;
    __syncthreads();
    int base = k * EPB;
    for (int i = t; i < EPB; i += 256) {
        int e = base + i;
        if (e < NE) atomicAdd(&lcnt[dst[e] >> 9], 1);
    }
    __syncthreads();
    if (t < NBIN2) hist[t * NCHUNK + k] = lcnt[t];   // [bin][chunk]
}

// ---------------- A2: per-bin scan over chunks (padded to 16) ----------------
__global__ __launch_bounds__(256) void k_scanA2a(const int* __restrict__ hist,
                                                 int* __restrict__ pbase,
                                                 int* __restrict__ ptot,
                                                 int* __restrict__ ttot) {
    __shared__ int shp[256];
    __shared__ int shv[256];
    int b = blockIdx.x, t = threadIdx.x;
    int v = hist[b * NCHUNK + t];
    int pv = (v + 15) & ~15;
    shp[t] = pv; shv[t] = v;
    __syncthreads();
    for (int d = 1; d < 256; d <<= 1) {
        int a1 = (t >= d) ? shp[t - d] : 0;
        int a2 = (t >= d) ? shv[t - d] : 0;
        __syncthreads();
        shp[t] += a1; shv[t] += a2;
        __syncthreads();
    }
    pbase[b * NCHUNK + t] = shp[t] - pv;   // exclusive padded base
    if (t == 255) { ptot[b] = shp[255]; ttot[b] = shv[255]; }
}

// ---------------- A3: deterministic placement (no global atomics) ----------------
__global__ __launch_bounds__(256) void k_placeA3(const int* __restrict__ src,
                                                 const int* __restrict__ dst,
                                                 const int* __restrict__ pbase,
                                                 unsigned int* __restrict__ pairs) {
    __shared__ int sbase[NBIN2];
    __shared__ int lcur[NBIN2];
    int k = blockIdx.x, t = threadIdx.x;
    if (t < NBIN2) { sbase[t] = pbase[t * NCHUNK + k]; lcur[t] = 0; }
    __syncthreads();
    int base = k * EPB;
    for (int i = t; i < EPB; i += 256) {
        int e = base + i;
        if (e < NE) {
            int s = src[e], d = dst[e];
            int b = d >> 9;
            int pos = atomicAdd(&lcur[b], 1);
            pairs[(unsigned)(b * CAPBIN + sbase[b] + pos)] =
                ((unsigned int)s << 9) | (unsigned int)(d & 511);
        }
    }
    __syncthreads();
    for (int b = t; b < NBIN2; b += 256) {
        int cnt = lcur[b];
        int end = sbase[b] + cnt;
        int pend = sbase[b] + ((cnt + 15) & ~15);
        for (int i = end; i < pend; ++i)
            pairs[(unsigned)(b * CAPBIN + i)] = SENT;
    }
}

// ---------------- B: per-bin (incl. inline 196-scan) -> off + ssrc ----------------
__global__ __launch_bounds__(512) void k_binPlace(const unsigned int* __restrict__ pairs,
                                                  const int* __restrict__ ptot,
                                                  const int* __restrict__ ttot,
                                                  int* __restrict__ off,
                                                  int* __restrict__ ssrc) {
    __shared__ int sbuf[9472];
    __shared__ int lcnt[512];
    __shared__ int sstart[512];
    __shared__ int lcur[512];
    __shared__ int sscan[512];
    __shared__ int stmp[512];
    __shared__ int sBB;
    int b = blockIdx.x, t = threadIdx.x;
    int tv = (t < NBIN2) ? ttot[t] : 0;
    stmp[t] = tv;
    lcnt[t] = 0; lcur[t] = 0;
    __syncthreads();
    for (int d = 1; d < 512; d <<= 1) {
        int add = (t >= d) ? stmp[t - d] : 0;
        __syncthreads();
        stmp[t] += add;
        __syncthreads();
    }
    if (t == 0) {
        sBB = (b == 0) ? 0 : stmp[b - 1];
        if (b == 0) off[NN] = NE;
    }
    __syncthreads();
    int bbase = sBB;
    int n = ptot[b];
    const unsigned int* pp = pairs + (unsigned)(b * CAPBIN);
    for (int i = t; i < n; i += 512) {
        unsigned int p = pp[i];
        if (p != SENT) atomicAdd(&lcnt[p & 511], 1);
    }
    __syncthreads();
    int vv = lcnt[t];
    sscan[t] = vv;
    __syncthreads();
    for (int d = 1; d < 512; d <<= 1) {
        int add = (t >= d) ? sscan[t - d] : 0;
        __syncthreads();
        sscan[t] += add;
        __syncthreads();
    }
    sstart[t] = sscan[t] - vv;
    int node = b * 512 + t;
    if (node < NN) off[node] = bbase + sstart[t];
    __syncthreads();
    for (int i = t; i < n; i += 512) {
        unsigned int p = pp[i];
        if (p != SENT) {
            int dl = p & 511;
            int lp = atomicAdd(&lcur[dl], 1);
            sbuf[sstart[dl] + lp] = (int)(p >> 9);
        }
    }
    __syncthreads();
    int len = sscan[511];
    for (int i = t; i < len; i += 512)
        ssrc[bbase + i] = sbuf[i];
}

// ---------------- fused: convert x -> bf16 (blocks 0..12499) + weight prep (block 12500) ----------------
__global__ __launch_bounds__(256) void k_cvt_prep(const float* __restrict__ x,
                                                  unsigned short* __restrict__ Axcat,
                                                  const float* __restrict__ W1l,
                                                  const float* __restrict__ W1r,
                                                  const float* __restrict__ W2l,
                                                  const float* __restrict__ W2r,
                                                  unsigned short* __restrict__ Wcat1t,
                                                  unsigned short* __restrict__ Wcat2t) {
    if (blockIdx.x == 12500) {
        for (int i = threadIdx.x; i < 128 * 128; i += 256) {
            int n = i >> 7, k = i & 127;
            float v1 = (k < 64) ? W1l[k * 128 + n] : W1r[(k - 64) * 128 + n];
            Wcat1t[i] = f2bf(v1);
            float v2 = (n < 64) ? W2l[k * 64 + n] : W2r[k * 64 + (n - 64)];
            Wcat2t[i] = f2bf(v2);
        }
        return;
    }
    unsigned idx = blockIdx.x * 256 + threadIdx.x;  // node*32 + f2
    if (idx >= NN * 32u) return;
    unsigned node = idx >> 5, f2 = idx & 31;
    float2 v = *(const float2*)(x + (unsigned)(node * 64 + 2 * f2));
    unsigned int p = (unsigned int)f2bf(v.x) | ((unsigned int)f2bf(v.y) << 16);
    *(unsigned int*)(Axcat + (unsigned)(node * 128 + 64 + 2 * f2)) = p;
}

// ---------------- gather-mean (8-deep MLP, 32-bit indices) ----------------
// half-wave (32 lanes) per node; lane covers 2 feats (uint); 8 feature-loads in flight.
__global__ __launch_bounds__(256) void k_gather_x(const int* __restrict__ ssrc,
                                                  const int* __restrict__ off,
                                                  unsigned short* __restrict__ Axcat) {
    int wv = (blockIdx.x * blockDim.x + threadIdx.x) >> 6;
    int half = (threadIdx.x >> 5) & 1;
    int lane = threadIdx.x & 31;
    int node = wv * 2 + half;
    if (node >= NN) return;
    int o0 = off[node], o1 = off[node + 1];
    unsigned fo = 64u + 2u * lane;   // feature byte-pair offset within row
    float a0 = 0.f, a1 = 0.f;
    for (int base = o0; base < o1; base += 32) {
        int nk = min(32, o1 - base);
        int sidx = (base + lane < o1) ? ssrc[base + lane] : 0;
        int k = 0;
        for (; k + 7 < nk; k += 8) {
            unsigned int v0 = *(const unsigned int*)(Axcat + ((unsigned)__shfl(sidx, k    , 32) * 128u + fo));
            unsigned int v1 = *(const unsigned int*)(Axcat + ((unsigned)__shfl(sidx, k + 1, 32) * 128u + fo));
            unsigned int v2 = *(const unsigned int*)(Axcat + ((unsigned)__shfl(sidx, k + 2, 32) * 128u + fo));
            unsigned int v3 = *(const unsigned int*)(Axcat + ((unsigned)__shfl(sidx, k + 3, 32) * 128u + fo));
            unsigned int v4 = *(const unsigned int*)(Axcat + ((unsigned)__shfl(sidx, k + 4, 32) * 128u + fo));
            unsigned int v5 = *(const unsigned int*)(Axcat + ((unsigned)__shfl(sidx, k + 5, 32) * 128u + fo));
            unsigned int v6 = *(const unsigned int*)(Axcat + ((unsigned)__shfl(sidx, k + 6, 32) * 128u + fo));
            unsigned int v7 = *(const unsigned int*)(Axcat + ((unsigned)__shfl(sidx, k + 7, 32) * 128u + fo));
            a0 += bf2f((unsigned short)v0) + bf2f((unsigned short)v1)
                + bf2f((unsigned short)v2) + bf2f((unsigned short)v3)
                + bf2f((unsigned short)v4) + bf2f((unsigned short)v5)
                + bf2f((unsigned short)v6) + bf2f((unsigned short)v7);
            a1 += bf2f((unsigned short)(v0 >> 16)) + bf2f((unsigned short)(v1 >> 16))
                + bf2f((unsigned short)(v2 >> 16)) + bf2f((unsigned short)(v3 >> 16))
                + bf2f((unsigned short)(v4 >> 16)) + bf2f((unsigned short)(v5 >> 16))
                + bf2f((unsigned short)(v6 >> 16)) + bf2f((unsigned short)(v7 >> 16));
        }
        for (; k + 3 < nk; k += 4) {
            unsigned int v0 = *(const unsigned int*)(Axcat + ((unsigned)__shfl(sidx, k    , 32) * 128u + fo));
            unsigned int v1 = *(const unsigned int*)(Axcat + ((unsigned)__shfl(sidx, k + 1, 32) * 128u + fo));
            unsigned int v2 = *(const unsigned int*)(Axcat + ((unsigned)__shfl(sidx, k + 2, 32) * 128u + fo));
            unsigned int v3 = *(const unsigned int*)(Axcat + ((unsigned)__shfl(sidx, k + 3, 32) * 128u + fo));
            a0 += bf2f((unsigned short)v0) + bf2f((unsigned short)v1)
                + bf2f((unsigned short)v2) + bf2f((unsigned short)v3);
            a1 += bf2f((unsigned short)(v0 >> 16)) + bf2f((unsigned short)(v1 >> 16))
                + bf2f((unsigned short)(v2 >> 16)) + bf2f((unsigned short)(v3 >> 16));
        }
        for (; k < nk; ++k) {
            unsigned int v0 = *(const unsigned int*)(Axcat + ((unsigned)__shfl(sidx, k, 32) * 128u + fo));
            a0 += bf2f((unsigned short)v0);
            a1 += bf2f((unsigned short)(v0 >> 16));
        }
    }
    int deg = o1 - o0;
    float inv = (deg > 0) ? 1.f / (float)deg : 0.f;
    unsigned int p = (unsigned int)f2bf(a0 * inv) | ((unsigned int)f2bf(a1 * inv) << 16);
    *(unsigned int*)(Axcat + ((unsigned)node * 128u + 2u * lane)) = p;
}

// ---------------- gather-mean of y1 + z + relu -> out (8-deep MLP, 32-bit indices) ----------------
__global__ __launch_bounds__(256) void k_gather_out(const int* __restrict__ ssrc,
                                                    const int* __restrict__ off,
                                                    const unsigned short* __restrict__ y1b,
                                                    const unsigned short* __restrict__ zb,
                                                    float* __restrict__ out) {
    int wv = (blockIdx.x * blockDim.x + threadIdx.x) >> 6;
    int half = (threadIdx.x >> 5) & 1;
    int lane = threadIdx.x & 31;
    int node = wv * 2 + half;
    if (node >= NN) return;
    int o0 = off[node], o1 = off[node + 1];
    unsigned fo = 2u * lane;
    float a0 = 0.f, a1 = 0.f;
    for (int base = o0; base < o1; base += 32) {
        int nk = min(32, o1 - base);
        int sidx = (base + lane < o1) ? ssrc[base + lane] : 0;
        int k = 0;
        for (; k + 7 < nk; k += 8) {
            unsigned int v0 = *(const unsigned int*)(y1b + ((unsigned)__shfl(sidx, k    , 32) * 64u + fo));
            unsigned int v1 = *(const unsigned int*)(y1b + ((unsigned)__shfl(sidx, k + 1, 32) * 64u + fo));
            unsigned int v2 = *(const unsigned int*)(y1b + ((unsigned)__shfl(sidx, k + 2, 32) * 64u + fo));
            unsigned int v3 = *(const unsigned int*)(y1b + ((unsigned)__shfl(sidx, k + 3, 32) * 64u + fo));
            unsigned int v4 = *(const unsigned int*)(y1b + ((unsigned)__shfl(sidx, k + 4, 32) * 64u + fo));
            unsigned int v5 = *(const unsigned int*)(y1b + ((unsigned)__shfl(sidx, k + 5, 32) * 64u + fo));
            unsigned int v6 = *(const unsigned int*)(y1b + ((unsigned)__shfl(sidx, k + 6, 32) * 64u + fo));
            unsigned int v7 = *(const unsigned int*)(y1b + ((unsigned)__shfl(sidx, k + 7, 32) * 64u + fo));
            a0 += bf2f((unsigned short)v0) + bf2f((unsigned short)v1)
                + bf2f((unsigned short)v2) + bf2f((unsigned short)v3)
                + bf2f((unsigned short)v4) + bf2f((unsigned short)v5)
                + bf2f((unsigned short)v6) + bf2f((unsigned short)v7);
            a1 += bf2f((unsigned short)(v0 >> 16)) + bf2f((unsigned short)(v1 >> 16))
                + bf2f((unsigned short)(v2 >> 16)) + bf2f((unsigned short)(v3 >> 16))
                + bf2f((unsigned short)(v4 >> 16)) + bf2f((unsigned short)(v5 >> 16))
                + bf2f((unsigned short)(v6 >> 16)) + bf2f((unsigned short)(v7 >> 16));
        }
        for (; k + 3 < nk; k += 4) {
            unsigned int v0 = *(const unsigned int*)(y1b + ((unsigned)__shfl(sidx, k    , 32) * 64u + fo));
            unsigned int v1 = *(const unsigned int*)(y1b + ((unsigned)__shfl(sidx, k + 1, 32) * 64u + fo));
            unsigned int v2 = *(const unsigned int*)(y1b + ((unsigned)__shfl(sidx, k + 2, 32) * 64u + fo));
            unsigned int v3 = *(const unsigned int*)(y1b + ((unsigned)__shfl(sidx, k + 3, 32) * 64u + fo));
            a0 += bf2f((unsigned short)v0) + bf2f((unsigned short)v1)
                + bf2f((unsigned short)v2) + bf2f((unsigned short)v3);
            a1 += bf2f((unsigned short)(v0 >> 16)) + bf2f((unsigned short)(v1 >> 16))
                + bf2f((unsigned short)(v2 >> 16)) + bf2f((unsigned short)(v3 >> 16));
        }
        for (; k < nk; ++k) {
            unsigned int v0 = *(const unsigned int*)(y1b + ((unsigned)__shfl(sidx, k, 32) * 64u + fo));
            a0 += bf2f((unsigned short)v0);
            a1 += bf2f((unsigned short)(v0 >> 16));
        }
    }
    int deg = o1 - o0;
    float inv = (deg > 0) ? 1.f / (float)deg : 0.f;
    unsigned int zz = *(const unsigned int*)(zb + ((unsigned)node * 64u + fo));
    float2 o;
    o.x = fmaxf(a0 * inv + bf2f((unsigned short)zz), 0.f);
    o.y = fmaxf(a1 * inv + bf2f((unsigned short)(zz >> 16)), 0.f);
    *(float2*)(out + ((unsigned)node * 64u + fo)) = o;
}

// ---------------- fused MFMA GEMM: h1 = relu(A@Wc1+b1) in-LDS, then y1|z = h1@Wc2 ----------------
__global__ __launch_bounds__(256) void k_gemm_fused(
    const unsigned short* __restrict__ A,
    const unsigned short* __restrict__ Bt1,
    const unsigned short* __restrict__ Bt2,
    const float* __restrict__ b1,
    const float* __restrict__ b2,
    unsigned short* __restrict__ y1b,
    unsigned short* __restrict__ zb) {
    __shared__ unsigned short lds[3 * 128 * 128];  // [0,32K) A then h1; [32K,64K) Wc1; [64K,96K) Wc2
    __shared__ float sB1[128];
    __shared__ float sB2[128];
    const int tid = threadIdx.x;
    const int wid = tid >> 6;
    const int lane = tid & 63;

    if (tid < 128) {
        sB1[tid] = b1[tid];
        sB2[tid] = (tid >= 64) ? b2[tid - 64] : 0.f;
    }

    const char* Ag  = (const char*)(A + (unsigned)(blockIdx.x * 128 * 128));
    const char* B1g = (const char*)Bt1;
    const char* B2g = (const char*)Bt2;
    char* ldsc = (char*)lds;
    #pragma unroll
    for (int j = 0; j < 8; ++j) {
        int g = wid * 512 + j * 64 + lane;        // granule (16B) index in [0,2048)
        int gs = g ^ ((g >> 4) & 7);              // pre-swizzled source granule
        GLOAD_LDS16(Ag  + (unsigned)(gs * 16), ldsc + (wid * 8192 + j * 1024));
        GLOAD_LDS16(B1g + (unsigned)(gs * 16), ldsc + 32768 + (wid * 8192 + j * 1024));
        GLOAD_LDS16(B2g + (unsigned)(gs * 16), ldsc + 65536 + (wid * 8192 + j * 1024));
    }
    __syncthreads();

    const int rA = lane & 15;
    const int kq = lane >> 4;                     // 0..3
    f32x4 acc[2][8] = {};

    // ---- pass 1: h1 = A @ Wc1 ----
    #pragma unroll
    for (int ks = 0; ks < 4; ++ks) {
        const int kbyte = ks * 64 + kq * 16;
        bf16x8 a[2], b[8];
        #pragma unroll
        for (int m = 0; m < 2; ++m) {
            int row = wid * 32 + m * 16 + rA;
            a[m] = *(const bf16x8*)(ldsc + row * 256 + (kbyte ^ ((row & 7) << 4)));
        }
        #pragma unroll
        for (int n = 0; n < 8; ++n) {
            int row = n * 16 + rA;
            b[n] = *(const bf16x8*)(ldsc + 32768 + row * 256 + (kbyte ^ ((row & 7) << 4)));
        }
        #pragma unroll
        for (int m = 0; m < 2; ++m)
            #pragma unroll
            for (int n = 0; n < 8; ++n)
                acc[m][n] = __builtin_amdgcn_mfma_f32_16x16x32_bf16(a[m], b[n], acc[m][n], 0, 0, 0);
    }
    __syncthreads();

    // ---- write h1 = relu(acc + b1) into region 0, same swizzle as A reads ----
    #pragma unroll
    for (int m = 0; m < 2; ++m) {
        #pragma unroll
        for (int n = 0; n < 8; ++n) {
            int col = n * 16 + rA;
            int row0 = wid * 32 + m * 16 + kq * 4;
            #pragma unroll
            for (int r = 0; r < 4; ++r) {
                int row = row0 + r;
                float v = fmaxf(acc[m][n][r] + sB1[col], 0.f);
                *(unsigned short*)(ldsc + row * 256 + ((2 * col) ^ ((row & 7) << 4))) = f2bf(v);
            }
            acc[m][n] = f32x4{0.f, 0.f, 0.f, 0.f};
        }
    }
    __syncthreads();

    // ---- pass 2: [y1|z] = h1 @ Wc2 ----
    #pragma unroll
    for (int ks = 0; ks < 4; ++ks) {
        const int kbyte = ks * 64 + kq * 16;
        bf16x8 a[2], b[8];
        #pragma unroll
        for (int m = 0; m < 2; ++m) {
            int row = wid * 32 + m * 16 + rA;
            a[m] = *(const bf16x8*)(ldsc + row * 256 + (kbyte ^ ((row & 7) << 4)));
        }
        #pragma unroll
        for (int n = 0; n < 8; ++n) {
            int row = n * 16 + rA;
            b[n] = *(const bf16x8*)(ldsc + 65536 + row * 256 + (kbyte ^ ((row & 7) << 4)));
        }
        #pragma unroll
        for (int m = 0; m < 2; ++m)
            #pragma unroll
            for (int n = 0; n < 8; ++n)
                acc[m][n] = __builtin_amdgcn_mfma_f32_16x16x32_bf16(a[m], b[n], acc[m][n], 0, 0, 0);
    }

    #pragma unroll
    for (int m = 0; m < 2; ++m) {
        #pragma unroll
        for (int n = 0; n < 8; ++n) {
            int col = n * 16 + rA;
            int row0 = blockIdx.x * 128 + wid * 32 + m * 16 + kq * 4;
            #pragma unroll
            for (int r = 0; r < 4; ++r) {
                int row = row0 + r;
                if (row < NN) {
                    float v = acc[m][n][r];
                    if (col < 64) y1b[(unsigned)(row * 64 + col)] = f2bf(v);
                    else          zb[(unsigned)(row * 64 + (col - 64))] = f2bf(v + sB2[col]);
                }
            }
        }
    }
}

extern "C" void kernel_launch(void* const* d_in, const int* in_sizes, int n_in,
                              void* d_out, int out_size, void* d_ws, size_t ws_size,
                              hipStream_t stream) {
    const float* x   = (const float*)d_in[0];
    const int*   ei  = (const int*)d_in[1];
    const int*   src = ei;
    const int*   dst = ei + NE;
    const float* W1l = (const float*)d_in[2];
    const float* b1  = (const float*)d_in[3];
    const float* W1r = (const float*)d_in[4];
    const float* W2l = (const float*)d_in[5];
    const float* b2  = (const float*)d_in[6];
    const float* W2r = (const float*)d_in[7];
    float* out = (float*)d_out;

    // workspace layout (bytes), all buffers fully written before read (no memset):
    //   [0,        400640)    off    int[NN+1]
    //   [400640,   6800640)   ssrc   int[NE]
    //   [6800640,  7001344)   hist   int[NBIN2*NCHUNK]
    //   [7001344,  7202048)   pbase  int[NBIN2*NCHUNK]
    //   [7202048,  7203072)   ptot   int[256]
    //   [7203072,  7204096)   ttot   int[256]
    //   [7204096,  17640704)  pairs  uint[NBIN2*CAPBIN]
    //   [17640704, 43265280)  Axcat  bf16[NROWS][128]
    //   [43265280, 56065280)  y1b    bf16[NN][64]
    //   [56065280, 68865280)  zb     bf16[NN][64]
    //   [68865280, 68898048)  Wc1    bf16[128][128]
    //   [68898048, 68930816)  Wc2    bf16[128][128]
    char* ws = (char*)d_ws;
    int*   off   = (int*)ws;
    int*   ssrc  = (int*)(ws + 400640);
    int*   hist  = (int*)(ws + 6800640);
    int*   pbase = (int*)(ws + 7001344);
    int*   ptot  = (int*)(ws + 7202048);
    int*   ttot  = (int*)(ws + 7203072);
    unsigned int* pairs = (unsigned int*)(ws + 7204096);
    unsigned short* Axcat = (unsigned short*)(ws + 17640704);
    unsigned short* y1b   = (unsigned short*)(ws + 43265280);
    unsigned short* zb    = (unsigned short*)(ws + 56065280);
    unsigned short* Wc1   = (unsigned short*)(ws + 68865280);
    unsigned short* Wc2   = (unsigned short*)(ws + 68898048);

    k_hist<<<NCHUNK, 256, 0, stream>>>(dst, hist);
    k_scanA2a<<<NBIN2, 256, 0, stream>>>(hist, pbase, ptot, ttot);
    k_placeA3<<<NCHUNK, 256, 0, stream>>>(src, dst, pbase, pairs);
    k_binPlace<<<NBIN2, 512, 0, stream>>>(pairs, ptot, ttot, off, ssrc);
    k_cvt_prep<<<12501, 256, 0, stream>>>(x, Axcat, W1l, W1r, W2l, W2r, Wc1, Wc2);
    k_gather_x<<<(NN / 2 * 64 + 255) / 256, 256, 0, stream>>>(ssrc, off, Axcat);
    k_gemm_fused<<<NROWS / 128, 256, 0, stream>>>(Axcat, Wc1, Wc2, b1, b2, y1b, zb);
    k_gather_out<<<(NN / 2 * 64 + 255) / 256, 256, 0, stream>>>(ssrc, off, y1b, zb, out);
}

// Round 14
// 238.837 us; speedup vs baseline: 1.0547x; 1.0212x over previous
//
#include <hip/hip_runtime.h>
#include <hip/hip_bf16.h>
#include <hip/hip_fp8.h>

#define NN 100000
#define NE 1600000
#define NROWS 100096   // 782 * 128, padded row count for GEMM tiles
#define NBIN2 196      // ceil(NN/512) bins of 512 nodes (dst>>9)
#define NCHUNK 256     // edge chunks (= placement blocks)
#define EPB 6250       // edges per chunk (256*6250 = NE exactly)
#define CAPBIN 13312   // padded per-bin capacity (mean 8163 + pad <=3840 + slack)
#define SENT 0xFFFFFFFFu

typedef short bf16x8 __attribute__((ext_vector_type(8)));
typedef float f32x4 __attribute__((ext_vector_type(4)));

static __device__ __forceinline__ unsigned short f2bf(float f) {
    __hip_bfloat16 h = __float2bfloat16(f);
    return *reinterpret_cast<unsigned short*>(&h);
}
static __device__ __forceinline__ float bf2f(unsigned short u) {
    union { unsigned int i; float f; } v;
    v.i = ((unsigned int)u) << 16;
    return v.f;
}
static __device__ __forceinline__ unsigned char f2fp8(float f) {
    __hip_fp8_e4m3 h(f);            // OCP e4m3fn on gfx950
    return h.__x;
}
static __device__ __forceinline__ float fp82f(unsigned char u) {
    __hip_fp8_e4m3 h;
    h.__x = u;
    return (float)h;
}

#define GLOAD_LDS16(g, l) \
    __builtin_amdgcn_global_load_lds((const __attribute__((address_space(1))) void*)(g), \
                                     (__attribute__((address_space(3))) void*)(l), 16, 0, 0)

// ---------------- A1: per-chunk histogram over 196 bins ----------------
__global__ __launch_bounds__(256) void k_hist(const int* __restrict__ dst,
                                              int* __restrict__ hist) {
    __shared__ int lcnt[NBIN2];
    int k = blockIdx.x, t = threadIdx.x;
    if (t < NBIN2) lcnt[t] = 0;
    __syncthreads();
    int base = k * EPB;
    for (int i = t; i < EPB; i += 256) {
        int e = base + i;
        if (e < NE) atomicAdd(&lcnt[dst[e] >> 9], 1);
    }
    __syncthreads();
    if (t < NBIN2) hist[t * NCHUNK + k] = lcnt[t];   // [bin][chunk]
}

// ---------------- A2: per-bin scan over chunks (padded to 16) ----------------
__global__ __launch_bounds__(256) void k_scanA2a(const int* __restrict__ hist,
                                                 int* __restrict__ pbase,
                                                 int* __restrict__ ptot,
                                                 int* __restrict__ ttot) {
    __shared__ int shp[256];
    __shared__ int shv[256];
    int b = blockIdx.x, t = threadIdx.x;
    int v = hist[b * NCHUNK + t];
    int pv = (v + 15) & ~15;
    shp[t] = pv; shv[t] = v;
    __syncthreads();
    for (int d = 1; d < 256; d <<= 1) {
        int a1 = (t >= d) ? shp[t - d] : 0;
        int a2 = (t >= d) ? shv[t - d] : 0;
        __syncthreads();
        shp[t] += a1; shv[t] += a2;
        __syncthreads();
    }
    pbase[b * NCHUNK + t] = shp[t] - pv;   // exclusive padded base
    if (t == 255) { ptot[b] = shp[255]; ttot[b] = shv[255]; }
}

// ---------------- A3: deterministic placement (no global atomics) ----------------
__global__ __launch_bounds__(256) void k_placeA3(const int* __restrict__ src,
                                                 const int* __restrict__ dst,
                                                 const int* __restrict__ pbase,
                                                 unsigned int* __restrict__ pairs) {
    __shared__ int sbase[NBIN2];
    __shared__ int lcur[NBIN2];
    int k = blockIdx.x, t = threadIdx.x;
    if (t < NBIN2) { sbase[t] = pbase[t * NCHUNK + k]; lcur[t] = 0; }
    __syncthreads();
    int base = k * EPB;
    for (int i = t; i < EPB; i += 256) {
        int e = base + i;
        if (e < NE) {
            int s = src[e], d = dst[e];
            int b = d >> 9;
            int pos = atomicAdd(&lcur[b], 1);
            pairs[(unsigned)(b * CAPBIN + sbase[b] + pos)] =
                ((unsigned int)s << 9) | (unsigned int)(d & 511);
        }
    }
    __syncthreads();
    for (int b = t; b < NBIN2; b += 256) {
        int cnt = lcur[b];
        int end = sbase[b] + cnt;
        int pend = sbase[b] + ((cnt + 15) & ~15);
        for (int i = end; i < pend; ++i)
            pairs[(unsigned)(b * CAPBIN + i)] = SENT;
    }
}

// ---------------- B: per-bin (incl. inline 196-scan) -> off + ssrc ----------------
__global__ __launch_bounds__(512) void k_binPlace(const unsigned int* __restrict__ pairs,
                                                  const int* __restrict__ ptot,
                                                  const int* __restrict__ ttot,
                                                  int* __restrict__ off,
                                                  int* __restrict__ ssrc) {
    __shared__ int sbuf[9472];
    __shared__ int lcnt[512];
    __shared__ int sstart[512];
    __shared__ int lcur[512];
    __shared__ int sscan[512];
    __shared__ int stmp[512];
    __shared__ int sBB;
    int b = blockIdx.x, t = threadIdx.x;
    int tv = (t < NBIN2) ? ttot[t] : 0;
    stmp[t] = tv;
    lcnt[t] = 0; lcur[t] = 0;
    __syncthreads();
    for (int d = 1; d < 512; d <<= 1) {
        int add = (t >= d) ? stmp[t - d] : 0;
        __syncthreads();
        stmp[t] += add;
        __syncthreads();
    }
    if (t == 0) {
        sBB = (b == 0) ? 0 : stmp[b - 1];
        if (b == 0) off[NN] = NE;
    }
    __syncthreads();
    int bbase = sBB;
    int n = ptot[b];
    const unsigned int* pp = pairs + (unsigned)(b * CAPBIN);
    for (int i = t; i < n; i += 512) {
        unsigned int p = pp[i];
        if (p != SENT) atomicAdd(&lcnt[p & 511], 1);
    }
    __syncthreads();
    int vv = lcnt[t];
    sscan[t] = vv;
    __syncthreads();
    for (int d = 1; d < 512; d <<= 1) {
        int add = (t >= d) ? sscan[t - d] : 0;
        __syncthreads();
        sscan[t] += add;
        __syncthreads();
    }
    sstart[t] = sscan[t] - vv;
    int node = b * 512 + t;
    if (node < NN) off[node] = bbase + sstart[t];
    __syncthreads();
    for (int i = t; i < n; i += 512) {
        unsigned int p = pp[i];
        if (p != SENT) {
            int dl = p & 511;
            int lp = atomicAdd(&lcur[dl], 1);
            sbuf[sstart[dl] + lp] = (int)(p >> 9);
        }
    }
    __syncthreads();
    int len = sscan[511];
    for (int i = t; i < len; i += 512)
        ssrc[bbase + i] = sbuf[i];
}

// ---------------- fused: convert x -> bf16 (blocks 0..12499) + weight prep (block 12500) ----------------
__global__ __launch_bounds__(256) void k_cvt_prep(const float* __restrict__ x,
                                                  unsigned short* __restrict__ Axcat,
                                                  const float* __restrict__ W1l,
                                                  const float* __restrict__ W1r,
                                                  const float* __restrict__ W2l,
                                                  const float* __restrict__ W2r,
                                                  unsigned short* __restrict__ Wcat1t,
                                                  unsigned short* __restrict__ Wcat2t) {
    if (blockIdx.x == 12500) {
        for (int i = threadIdx.x; i < 128 * 128; i += 256) {
            int n = i >> 7, k = i & 127;
            float v1 = (k < 64) ? W1l[k * 128 + n] : W1r[(k - 64) * 128 + n];
            Wcat1t[i] = f2bf(v1);
            float v2 = (n < 64) ? W2l[k * 64 + n] : W2r[k * 64 + (n - 64)];
            Wcat2t[i] = f2bf(v2);
        }
        return;
    }
    unsigned idx = blockIdx.x * 256 + threadIdx.x;  // node*32 + f2
    if (idx >= NN * 32u) return;
    unsigned node = idx >> 5, f2 = idx & 31;
    float2 v = *(const float2*)(x + (unsigned)(node * 64 + 2 * f2));
    unsigned int p = (unsigned int)f2bf(v.x) | ((unsigned int)f2bf(v.y) << 16);
    *(unsigned int*)(Axcat + (unsigned)(node * 128 + 64 + 2 * f2)) = p;
}

// ---------------- gather-mean (8-deep MLP, 32-bit indices) ----------------
__global__ __launch_bounds__(256) void k_gather_x(const int* __restrict__ ssrc,
                                                  const int* __restrict__ off,
                                                  unsigned short* __restrict__ Axcat) {
    int wv = (blockIdx.x * blockDim.x + threadIdx.x) >> 6;
    int half = (threadIdx.x >> 5) & 1;
    int lane = threadIdx.x & 31;
    int node = wv * 2 + half;
    if (node >= NN) return;
    int o0 = off[node], o1 = off[node + 1];
    unsigned fo = 64u + 2u * lane;
    float a0 = 0.f, a1 = 0.f;
    for (int base = o0; base < o1; base += 32) {
        int nk = min(32, o1 - base);
        int sidx = (base + lane < o1) ? ssrc[base + lane] : 0;
        int k = 0;
        for (; k + 7 < nk; k += 8) {
            unsigned int v0 = *(const unsigned int*)(Axcat + ((unsigned)__shfl(sidx, k    , 32) * 128u + fo));
            unsigned int v1 = *(const unsigned int*)(Axcat + ((unsigned)__shfl(sidx, k + 1, 32) * 128u + fo));
            unsigned int v2 = *(const unsigned int*)(Axcat + ((unsigned)__shfl(sidx, k + 2, 32) * 128u + fo));
            unsigned int v3 = *(const unsigned int*)(Axcat + ((unsigned)__shfl(sidx, k + 3, 32) * 128u + fo));
            unsigned int v4 = *(const unsigned int*)(Axcat + ((unsigned)__shfl(sidx, k + 4, 32) * 128u + fo));
            unsigned int v5 = *(const unsigned int*)(Axcat + ((unsigned)__shfl(sidx, k + 5, 32) * 128u + fo));
            unsigned int v6 = *(const unsigned int*)(Axcat + ((unsigned)__shfl(sidx, k + 6, 32) * 128u + fo));
            unsigned int v7 = *(const unsigned int*)(Axcat + ((unsigned)__shfl(sidx, k + 7, 32) * 128u + fo));
            a0 += bf2f((unsigned short)v0) + bf2f((unsigned short)v1)
                + bf2f((unsigned short)v2) + bf2f((unsigned short)v3)
                + bf2f((unsigned short)v4) + bf2f((unsigned short)v5)
                + bf2f((unsigned short)v6) + bf2f((unsigned short)v7);
            a1 += bf2f((unsigned short)(v0 >> 16)) + bf2f((unsigned short)(v1 >> 16))
                + bf2f((unsigned short)(v2 >> 16)) + bf2f((unsigned short)(v3 >> 16))
                + bf2f((unsigned short)(v4 >> 16)) + bf2f((unsigned short)(v5 >> 16))
                + bf2f((unsigned short)(v6 >> 16)) + bf2f((unsigned short)(v7 >> 16));
        }
        for (; k + 3 < nk; k += 4) {
            unsigned int v0 = *(const unsigned int*)(Axcat + ((unsigned)__shfl(sidx, k    , 32) * 128u + fo));
            unsigned int v1 = *(const unsigned int*)(Axcat + ((unsigned)__shfl(sidx, k + 1, 32) * 128u + fo));
            unsigned int v2 = *(const unsigned int*)(Axcat + ((unsigned)__shfl(sidx, k + 2, 32) * 128u + fo));
            unsigned int v3 = *(const unsigned int*)(Axcat + ((unsigned)__shfl(sidx, k + 3, 32) * 128u + fo));
            a0 += bf2f((unsigned short)v0) + bf2f((unsigned short)v1)
                + bf2f((unsigned short)v2) + bf2f((unsigned short)v3);
            a1 += bf2f((unsigned short)(v0 >> 16)) + bf2f((unsigned short)(v1 >> 16))
                + bf2f((unsigned short)(v2 >> 16)) + bf2f((unsigned short)(v3 >> 16));
        }
        for (; k < nk; ++k) {
            unsigned int v0 = *(const unsigned int*)(Axcat + ((unsigned)__shfl(sidx, k, 32) * 128u + fo));
            a0 += bf2f((unsigned short)v0);
            a1 += bf2f((unsigned short)(v0 >> 16));
        }
    }
    int deg = o1 - o0;
    float inv = (deg > 0) ? 1.f / (float)deg : 0.f;
    unsigned int p = (unsigned int)f2bf(a0 * inv) | ((unsigned int)f2bf(a1 * inv) << 16);
    *(unsigned int*)(Axcat + ((unsigned)node * 128u + 2u * lane)) = p;
}

// ---------------- gather-mean of fp8 y1 + bf16 z + relu -> out (8-deep MLP) ----------------
// y8 rows are 64 B: lane loads 2 B (feats 2*lane, 2*lane+1).
__global__ __launch_bounds__(256) void k_gather_out(const int* __restrict__ ssrc,
                                                    const int* __restrict__ off,
                                                    const unsigned char* __restrict__ y8,
                                                    const unsigned short* __restrict__ zb,
                                                    float* __restrict__ out) {
    int wv = (blockIdx.x * blockDim.x + threadIdx.x) >> 6;
    int half = (threadIdx.x >> 5) & 1;
    int lane = threadIdx.x & 31;
    int node = wv * 2 + half;
    if (node >= NN) return;
    int o0 = off[node], o1 = off[node + 1];
    unsigned fo = 2u * lane;   // byte offset in 64 B row
    float a0 = 0.f, a1 = 0.f;
    for (int base = o0; base < o1; base += 32) {
        int nk = min(32, o1 - base);
        int sidx = (base + lane < o1) ? ssrc[base + lane] : 0;
        int k = 0;
        for (; k + 7 < nk; k += 8) {
            unsigned short v0 = *(const unsigned short*)(y8 + ((unsigned)__shfl(sidx, k    , 32) * 64u + fo));
            unsigned short v1 = *(const unsigned short*)(y8 + ((unsigned)__shfl(sidx, k + 1, 32) * 64u + fo));
            unsigned short v2 = *(const unsigned short*)(y8 + ((unsigned)__shfl(sidx, k + 2, 32) * 64u + fo));
            unsigned short v3 = *(const unsigned short*)(y8 + ((unsigned)__shfl(sidx, k + 3, 32) * 64u + fo));
            unsigned short v4 = *(const unsigned short*)(y8 + ((unsigned)__shfl(sidx, k + 4, 32) * 64u + fo));
            unsigned short v5 = *(const unsigned short*)(y8 + ((unsigned)__shfl(sidx, k + 5, 32) * 64u + fo));
            unsigned short v6 = *(const unsigned short*)(y8 + ((unsigned)__shfl(sidx, k + 6, 32) * 64u + fo));
            unsigned short v7 = *(const unsigned short*)(y8 + ((unsigned)__shfl(sidx, k + 7, 32) * 64u + fo));
            a0 += fp82f((unsigned char)v0) + fp82f((unsigned char)v1)
                + fp82f((unsigned char)v2) + fp82f((unsigned char)v3)
                + fp82f((unsigned char)v4) + fp82f((unsigned char)v5)
                + fp82f((unsigned char)v6) + fp82f((unsigned char)v7);
            a1 += fp82f((unsigned char)(v0 >> 8)) + fp82f((unsigned char)(v1 >> 8))
                + fp82f((unsigned char)(v2 >> 8)) + fp82f((unsigned char)(v3 >> 8))
                + fp82f((unsigned char)(v4 >> 8)) + fp82f((unsigned char)(v5 >> 8))
                + fp82f((unsigned char)(v6 >> 8)) + fp82f((unsigned char)(v7 >> 8));
        }
        for (; k + 3 < nk; k += 4) {
            unsigned short v0 = *(const unsigned short*)(y8 + ((unsigned)__shfl(sidx, k    , 32) * 64u + fo));
            unsigned short v1 = *(const unsigned short*)(y8 + ((unsigned)__shfl(sidx, k + 1, 32) * 64u + fo));
            unsigned short v2 = *(const unsigned short*)(y8 + ((unsigned)__shfl(sidx, k + 2, 32) * 64u + fo));
            unsigned short v3 = *(const unsigned short*)(y8 + ((unsigned)__shfl(sidx, k + 3, 32) * 64u + fo));
            a0 += fp82f((unsigned char)v0) + fp82f((unsigned char)v1)
                + fp82f((unsigned char)v2) + fp82f((unsigned char)v3);
            a1 += fp82f((unsigned char)(v0 >> 8)) + fp82f((unsigned char)(v1 >> 8))
                + fp82f((unsigned char)(v2 >> 8)) + fp82f((unsigned char)(v3 >> 8));
        }
        for (; k < nk; ++k) {
            unsigned short v0 = *(const unsigned short*)(y8 + ((unsigned)__shfl(sidx, k, 32) * 64u + fo));
            a0 += fp82f((unsigned char)v0);
            a1 += fp82f((unsigned char)(v0 >> 8));
        }
    }
    int deg = o1 - o0;
    float inv = (deg > 0) ? 1.f / (float)deg : 0.f;
    unsigned int zz = *(const unsigned int*)(zb + ((unsigned)node * 64u + fo));
    float2 o;
    o.x = fmaxf(a0 * inv + bf2f((unsigned short)zz), 0.f);
    o.y = fmaxf(a1 * inv + bf2f((unsigned short)(zz >> 16)), 0.f);
    *(float2*)(out + ((unsigned)node * 64u + fo)) = o;
}

// ---------------- fused MFMA GEMM: h1 = relu(A@Wc1+b1) in-LDS, then y1|z = h1@Wc2 ----------------
__global__ __launch_bounds__(256) void k_gemm_fused(
    const unsigned short* __restrict__ A,
    const unsigned short* __restrict__ Bt1,
    const unsigned short* __restrict__ Bt2,
    const float* __restrict__ b1,
    const float* __restrict__ b2,
    unsigned char* __restrict__ y8,
    unsigned short* __restrict__ zb) {
    __shared__ unsigned short lds[3 * 128 * 128];  // [0,32K) A then h1; [32K,64K) Wc1; [64K,96K) Wc2
    __shared__ float sB1[128];
    __shared__ float sB2[128];
    const int tid = threadIdx.x;
    const int wid = tid >> 6;
    const int lane = tid & 63;

    if (tid < 128) {
        sB1[tid] = b1[tid];
        sB2[tid] = (tid >= 64) ? b2[tid - 64] : 0.f;
    }

    const char* Ag  = (const char*)(A + (unsigned)(blockIdx.x * 128 * 128));
    const char* B1g = (const char*)Bt1;
    const char* B2g = (const char*)Bt2;
    char* ldsc = (char*)lds;
    #pragma unroll
    for (int j = 0; j < 8; ++j) {
        int g = wid * 512 + j * 64 + lane;        // granule (16B) index in [0,2048)
        int gs = g ^ ((g >> 4) & 7);              // pre-swizzled source granule
        GLOAD_LDS16(Ag  + (unsigned)(gs * 16), ldsc + (wid * 8192 + j * 1024));
        GLOAD_LDS16(B1g + (unsigned)(gs * 16), ldsc + 32768 + (wid * 8192 + j * 1024));
        GLOAD_LDS16(B2g + (unsigned)(gs * 16), ldsc + 65536 + (wid * 8192 + j * 1024));
    }
    __syncthreads();

    const int rA = lane & 15;
    const int kq = lane >> 4;                     // 0..3
    f32x4 acc[2][8] = {};

    // ---- pass 1: h1 = A @ Wc1 ----
    #pragma unroll
    for (int ks = 0; ks < 4; ++ks) {
        const int kbyte = ks * 64 + kq * 16;
        bf16x8 a[2], b[8];
        #pragma unroll
        for (int m = 0; m < 2; ++m) {
            int row = wid * 32 + m * 16 + rA;
            a[m] = *(const bf16x8*)(ldsc + row * 256 + (kbyte ^ ((row & 7) << 4)));
        }
        #pragma unroll
        for (int n = 0; n < 8; ++n) {
            int row = n * 16 + rA;
            b[n] = *(const bf16x8*)(ldsc + 32768 + row * 256 + (kbyte ^ ((row & 7) << 4)));
        }
        #pragma unroll
        for (int m = 0; m < 2; ++m)
            #pragma unroll
            for (int n = 0; n < 8; ++n)
                acc[m][n] = __builtin_amdgcn_mfma_f32_16x16x32_bf16(a[m], b[n], acc[m][n], 0, 0, 0);
    }
    __syncthreads();

    // ---- write h1 = relu(acc + b1) into region 0, same swizzle as A reads ----
    #pragma unroll
    for (int m = 0; m < 2; ++m) {
        #pragma unroll
        for (int n = 0; n < 8; ++n) {
            int col = n * 16 + rA;
            int row0 = wid * 32 + m * 16 + kq * 4;
            #pragma unroll
            for (int r = 0; r < 4; ++r) {
                int row = row0 + r;
                float v = fmaxf(acc[m][n][r] + sB1[col], 0.f);
                *(unsigned short*)(ldsc + row * 256 + ((2 * col) ^ ((row & 7) << 4))) = f2bf(v);
            }
            acc[m][n] = f32x4{0.f, 0.f, 0.f, 0.f};
        }
    }
    __syncthreads();

    // ---- pass 2: [y1|z] = h1 @ Wc2 ----
    #pragma unroll
    for (int ks = 0; ks < 4; ++ks) {
        const int kbyte = ks * 64 + kq * 16;
        bf16x8 a[2], b[8];
        #pragma unroll
        for (int m = 0; m < 2; ++m) {
            int row = wid * 32 + m * 16 + rA;
            a[m] = *(const bf16x8*)(ldsc + row * 256 + (kbyte ^ ((row & 7) << 4)));
        }
        #pragma unroll
        for (int n = 0; n < 8; ++n) {
            int row = n * 16 + rA;
            b[n] = *(const bf16x8*)(ldsc + 65536 + row * 256 + (kbyte ^ ((row & 7) << 4)));
        }
        #pragma unroll
        for (int m = 0; m < 2; ++m)
            #pragma unroll
            for (int n = 0; n < 8; ++n)
                acc[m][n] = __builtin_amdgcn_mfma_f32_16x16x32_bf16(a[m], b[n], acc[m][n], 0, 0, 0);
    }

    #pragma unroll
    for (int m = 0; m < 2; ++m) {
        #pragma unroll
        for (int n = 0; n < 8; ++n) {
            int col = n * 16 + rA;
            int row0 = blockIdx.x * 128 + wid * 32 + m * 16 + kq * 4;
            #pragma unroll
            for (int r = 0; r < 4; ++r) {
                int row = row0 + r;
                if (row < NN) {
                    float v = acc[m][n][r];
                    if (col < 64) y8[(unsigned)(row * 64 + col)] = f2fp8(v);
                    else          zb[(unsigned)(row * 64 + (col - 64))] = f2bf(v + sB2[col]);
                }
            }
        }
    }
}

extern "C" void kernel_launch(void* const* d_in, const int* in_sizes, int n_in,
                              void* d_out, int out_size, void* d_ws, size_t ws_size,
                              hipStream_t stream) {
    const float* x   = (const float*)d_in[0];
    const int*   ei  = (const int*)d_in[1];
    const int*   src = ei;
    const int*   dst = ei + NE;
    const float* W1l = (const float*)d_in[2];
    const float* b1  = (const float*)d_in[3];
    const float* W1r = (const float*)d_in[4];
    const float* W2l = (const float*)d_in[5];
    const float* b2  = (const float*)d_in[6];
    const float* W2r = (const float*)d_in[7];
    float* out = (float*)d_out;

    // workspace layout (bytes), all buffers fully written before read (no memset):
    //   [0,        400640)    off    int[NN+1]
    //   [400640,   6800640)   ssrc   int[NE]
    //   [6800640,  7001344)   hist   int[NBIN2*NCHUNK]
    //   [7001344,  7202048)   pbase  int[NBIN2*NCHUNK]
    //   [7202048,  7203072)   ptot   int[256]
    //   [7203072,  7204096)   ttot   int[256]
    //   [7204096,  17640704)  pairs  uint[NBIN2*CAPBIN]
    //   [17640704, 43265280)  Axcat  bf16[NROWS][128]
    //   [43265280, 49671424)  y8     fp8 [NROWS][64]
    //   [56065280, 68865280)  zb     bf16[NN][64]
    //   [68865280, 68898048)  Wc1    bf16[128][128]
    //   [68898048, 68930816)  Wc2    bf16[128][128]
    char* ws = (char*)d_ws;
    int*   off   = (int*)ws;
    int*   ssrc  = (int*)(ws + 400640);
    int*   hist  = (int*)(ws + 6800640);
    int*   pbase = (int*)(ws + 7001344);
    int*   ptot  = (int*)(ws + 7202048);
    int*   ttot  = (int*)(ws + 7203072);
    unsigned int* pairs = (unsigned int*)(ws + 7204096);
    unsigned short* Axcat = (unsigned short*)(ws + 17640704);
    unsigned char*  y8    = (unsigned char*)(ws + 43265280);
    unsigned short* zb    = (unsigned short*)(ws + 56065280);
    unsigned short* Wc1   = (unsigned short*)(ws + 68865280);
    unsigned short* Wc2   = (unsigned short*)(ws + 68898048);

    k_hist<<<NCHUNK, 256, 0, stream>>>(dst, hist);
    k_scanA2a<<<NBIN2, 256, 0, stream>>>(hist, pbase, ptot, ttot);
    k_placeA3<<<NCHUNK, 256, 0, stream>>>(src, dst, pbase, pairs);
    k_binPlace<<<NBIN2, 512, 0, stream>>>(pairs, ptot, ttot, off, ssrc);
    k_cvt_prep<<<12501, 256, 0, stream>>>(x, Axcat, W1l, W1r, W2l, W2r, Wc1, Wc2);
    k_gather_x<<<(NN / 2 * 64 + 255) / 256, 256, 0, stream>>>(ssrc, off, Axcat);
    k_gemm_fused<<<NROWS / 128, 256, 0, stream>>>(Axcat, Wc1, Wc2, b1, b2, y8, zb);
    k_gather_out<<<(NN / 2 * 64 + 255) / 256, 256, 0, stream>>>(ssrc, off, y8, zb, out);
}